// Round 1
// 496.586 us; speedup vs baseline: 1.0523x; 1.0523x over previous
//
#include <hip/hip_runtime.h>

#define N_NODES 100000
#define N_EDGES 600000
#define EPS_BN 1e-5f
#define EPS_NORM 1e-12f

typedef __attribute__((ext_vector_type(8))) short bf16x8;
typedef __attribute__((ext_vector_type(4))) float f32x4;

__device__ inline unsigned bf16u(float x) {
    unsigned b = __float_as_uint(x);
    return (b + 0x7FFF + ((b >> 16) & 1)) >> 16;
}
__device__ inline float bf16back(unsigned hb) { return __uint_as_float(hb << 16); }

// ===========================================================================
// CSR build: degree histogram -> exclusive scan -> cursor fill
// ===========================================================================
__global__ void k_deg(const int* __restrict__ dst, int* __restrict__ deg, int E) {
    int e = blockIdx.x * blockDim.x + threadIdx.x;
    if (e < E) atomicAdd(&deg[dst[e]], 1);
}

__global__ void k_scan1(const int* __restrict__ in, int* __restrict__ out,
                        int* __restrict__ bsum, int n) {
    __shared__ int s[256];
    int i = blockIdx.x * 256 + threadIdx.x;
    int v = (i < n) ? in[i] : 0;
    s[threadIdx.x] = v;
    __syncthreads();
#pragma unroll
    for (int off = 1; off < 256; off <<= 1) {
        int t = (threadIdx.x >= off) ? s[threadIdx.x - off] : 0;
        __syncthreads();
        s[threadIdx.x] += t;
        __syncthreads();
    }
    if (i < n) out[i] = s[threadIdx.x] - v;
    if (threadIdx.x == 255) bsum[blockIdx.x] = s[255];
}

__global__ void k_scan2(int* __restrict__ bsum, int nb) {
    __shared__ int s[512];
    int v = (threadIdx.x < nb) ? bsum[threadIdx.x] : 0;
    s[threadIdx.x] = v;
    __syncthreads();
#pragma unroll
    for (int off = 1; off < 512; off <<= 1) {
        int t = (threadIdx.x >= off) ? s[threadIdx.x - off] : 0;
        __syncthreads();
        s[threadIdx.x] += t;
        __syncthreads();
    }
    if (threadIdx.x < nb) bsum[threadIdx.x] = s[threadIdx.x] - v;
}

__global__ void k_prep(int* __restrict__ offs, const int* __restrict__ bsum,
                       const int* __restrict__ deg, int* __restrict__ cursor,
                       float* __restrict__ inv, int n, int E) {
    int i = blockIdx.x * 256 + threadIdx.x;
    if (i >= n) return;
    int o = offs[i] + bsum[i >> 8];
    offs[i] = o;
    cursor[i] = o;
    inv[i] = 1.0f / fmaxf((float)deg[i], 1.0f);
    if (i == 0) offs[n] = E;
}

__global__ void k_fill(const int* __restrict__ src, const int* __restrict__ dst,
                       int* __restrict__ cursor, int* __restrict__ adj, int E) {
    int e = blockIdx.x * blockDim.x + threadIdx.x;
    if (e < E) {
        int pos = atomicAdd(&cursor[dst[e]], 1);
        adj[pos] = src[e];
    }
}

// ===========================================================================
// Gather-aggregate (mean): one 64-lane wave per node, unroll x4 for MLP.
// ===========================================================================
__global__ void k_gather10(const float* __restrict__ h, const int* __restrict__ adj,
                           const int* __restrict__ offs, const float* __restrict__ inv,
                           float* __restrict__ mean, int n) {
    int node = (blockIdx.x * blockDim.x + threadIdx.x) >> 6;
    int lane = threadIdx.x & 63;
    if (node >= n) return;
    int beg = offs[node], end = offs[node + 1];
    float iv = inv[node];
    float acc = 0.0f;
    for (int p = beg; p < end; ++p) {
        int s = adj[p];
        if (lane < 10) acc += h[(size_t)s * 10 + lane];
    }
    if (lane < 10) mean[(size_t)node * 10 + lane] = acc * iv;
}

__global__ void k_gather64(const float* __restrict__ h, const int* __restrict__ adj,
                           const int* __restrict__ offs, const float* __restrict__ inv,
                           float* __restrict__ mean, int n) {
    int node = (blockIdx.x * blockDim.x + threadIdx.x) >> 6;
    int lane = threadIdx.x & 63;
    if (node >= n) return;
    int beg = offs[node], end = offs[node + 1];
    float iv = inv[node];
    float a0 = 0.0f, a1 = 0.0f, a2 = 0.0f, a3 = 0.0f;
    int p = beg;
    for (; p + 4 <= end; p += 4) {
        int s0 = adj[p], s1 = adj[p + 1], s2 = adj[p + 2], s3 = adj[p + 3];
        a0 += h[(size_t)s0 * 64 + lane];
        a1 += h[(size_t)s1 * 64 + lane];
        a2 += h[(size_t)s2 * 64 + lane];
        a3 += h[(size_t)s3 * 64 + lane];
    }
    for (; p < end; ++p) a0 += h[(size_t)adj[p] * 64 + lane];
    mean[(size_t)node * 64 + lane] = ((a0 + a1) + (a2 + a3)) * iv;
}

__global__ void k_gather128(const float* __restrict__ h, const int* __restrict__ adj,
                            const int* __restrict__ offs, const float* __restrict__ inv,
                            float* __restrict__ mean, int n) {
    int node = (blockIdx.x * blockDim.x + threadIdx.x) >> 6;
    int lane = threadIdx.x & 63;
    if (node >= n) return;
    int beg = offs[node], end = offs[node + 1];
    float iv = inv[node];
    float2 a0 = {0, 0}, a1 = {0, 0}, a2 = {0, 0}, a3 = {0, 0};
    int p = beg;
    for (; p + 4 <= end; p += 4) {
        int s0 = adj[p], s1 = adj[p + 1], s2 = adj[p + 2], s3 = adj[p + 3];
        float2 v0 = *(const float2*)&h[(size_t)s0 * 128 + lane * 2];
        float2 v1 = *(const float2*)&h[(size_t)s1 * 128 + lane * 2];
        float2 v2 = *(const float2*)&h[(size_t)s2 * 128 + lane * 2];
        float2 v3 = *(const float2*)&h[(size_t)s3 * 128 + lane * 2];
        a0.x += v0.x; a0.y += v0.y;
        a1.x += v1.x; a1.y += v1.y;
        a2.x += v2.x; a2.y += v2.y;
        a3.x += v3.x; a3.y += v3.y;
    }
    for (; p < end; ++p) {
        float2 v0 = *(const float2*)&h[(size_t)adj[p] * 128 + lane * 2];
        a0.x += v0.x; a0.y += v0.y;
    }
    float2 o = {((a0.x + a1.x) + (a2.x + a3.x)) * iv,
                ((a0.y + a1.y) + (a2.y + a3.y)) * iv};
    *(float2*)&mean[(size_t)node * 128 + lane * 2] = o;
}

// ===========================================================================
// Simple linear (layer 1: DIN=10, DOUT=64). mean already divided.
// ===========================================================================
template <int DIN, int DOUT, bool RELU>
__global__ void k_linear(const float* __restrict__ h, const float* __restrict__ mean,
                         const float* __restrict__ Wl, const float* __restrict__ Wr,
                         const float* __restrict__ bias,
                         const float* __restrict__ bn_g, const float* __restrict__ bn_b,
                         const float* __restrict__ bn_m, const float* __restrict__ bn_v,
                         float* __restrict__ out, int n) {
    int tid = blockIdx.x * blockDim.x + threadIdx.x;
    int node = tid / DOUT;
    int c = tid - node * DOUT;
    if (node >= n) return;

    const float* hr = h + (size_t)node * DIN;
    const float* mr = mean + (size_t)node * DIN;

    float acc = bias[c];
#pragma unroll
    for (int k = 0; k < DIN; ++k) {
        acc += mr[k] * Wl[k * DOUT + c] + hr[k] * Wr[k * DOUT + c];
    }
    float o = (acc - bn_m[c]) * rsqrtf(bn_v[c] + EPS_BN) * bn_g[c] + bn_b[c];
    if (RELU) o = fmaxf(o, 0.0f);
    out[(size_t)node * DOUT + c] = o;
}

// ===========================================================================
// Weight pre-swizzle into MFMA B-fragment order (hi/lo bf16 split).
// W = [Wl; Wr] stacked (K=2*DIN rows, 128 cols). B-frag layout for
// mfma_f32_16x16x32_bf16: lane holds n=lane&15, k=quad*8+j (j contiguous).
// wf[((ks*8+nt)*64+lane)*8+j] so the kernel loads 16 B/lane coalesced.
// ===========================================================================
template <int DIN>
__global__ void k_wprep(const float* __restrict__ Wl, const float* __restrict__ Wr,
                        unsigned short* __restrict__ wf_hi,
                        unsigned short* __restrict__ wf_lo) {
    constexpr int K = 2 * DIN;
    int t = blockIdx.x * 256 + threadIdx.x;
    if (t >= K * 128) return;
    int j = t & 7;
    int lane = (t >> 3) & 63;
    int nt = (t >> 9) & 7;
    int ks = t >> 12;
    int k = ks * 32 + (lane >> 4) * 8 + j;
    int nn = nt * 16 + (lane & 15);
    float v = (k < DIN) ? Wl[k * 128 + nn] : Wr[(k - DIN) * 128 + nn];
    unsigned hb = bf16u(v);
    float r = v - bf16back(hb);
    wf_hi[t] = (unsigned short)hb;
    wf_lo[t] = (unsigned short)bf16u(r);
}

// ===========================================================================
// MFMA linear+BN(+ReLU), DOUT=128, K=2*DIN (concat [mean,h]).
// bf16 hi/lo split: acc += Ahi*Bhi + Alo*Bhi + Ahi*Blo (lo*lo dropped,
// ~2^-18 relative). Block: 128 nodes, 4 independent waves, NO LDS and NO
// barriers: the A-fragment (m=lane&15, k=quad*8+j, j contiguous) is read
// directly from the row-major fp32 source as 2x float4 per lane and
// converted to bf16 hi/lo in registers. Each element is still read exactly
// once per chunk (the old LDS stage had zero reuse -- pure layout
// transform), but the vmcnt(0)-drain barriers and 400K bank-conflict
// cycles are gone, and loads pipeline freely across chunks.
// B-frags from pre-swizzled global (coalesced 16 B/lane, L2-hot).
// Verified layouts (m89/m120): A: m=lane&15,k=quad*8+j; B: n=lane&15,
// k=quad*8+j; C/D: col=lane&15, row=quad*4+reg.
// ===========================================================================
template <int DIN, bool RELU>
__global__ __launch_bounds__(256) void k_linear_mfma(
    const float* __restrict__ h, const float* __restrict__ mean,
    const unsigned short* __restrict__ wf_hi, const unsigned short* __restrict__ wf_lo,
    const float* __restrict__ bias,
    const float* __restrict__ bn_g, const float* __restrict__ bn_b,
    const float* __restrict__ bn_m, const float* __restrict__ bn_v,
    float* __restrict__ out, int n) {
    constexpr int CH = (2 * DIN) / 64;  // 64-k chunks

    const int tid = threadIdx.x;
    const int lane = tid & 63;
    const int wv = tid >> 6;
    const int quad = lane >> 4;
    const int l15 = lane & 15;
    const int node0 = blockIdx.x * 128;

    // clamped row indices for this lane's two m-tiles (A-frag rows)
    int row0 = node0 + wv * 32 + l15;
    int row1 = row0 + 16;
    if (row0 > n - 1) row0 = n - 1;
    if (row1 > n - 1) row1 = n - 1;

    f32x4 acc[2][8];
#pragma unroll
    for (int mt = 0; mt < 2; ++mt)
#pragma unroll
        for (int nt = 0; nt < 8; ++nt) acc[mt][nt] = {0.0f, 0.0f, 0.0f, 0.0f};

    for (int cc = 0; cc < CH; ++cc) {
        const int kbase = cc * 64;
        const float* srcp = (kbase < DIN) ? mean : h;
        const int coloff = ((kbase < DIN) ? kbase : kbase - DIN) + quad * 8;

        const float* rp0 = srcp + (size_t)row0 * DIN + coloff;
        const float* rp1 = srcp + (size_t)row1 * DIN + coloff;

#pragma unroll
        for (int ks = 0; ks < 2; ++ks) {
            const int ksg = cc * 2 + ks;
            // ---- direct A-fragment loads + fp32 -> bf16 hi/lo in registers
            bf16x8 aH[2], aL[2];
#pragma unroll
            for (int mt = 0; mt < 2; ++mt) {
                const float* rp = (mt == 0 ? rp0 : rp1) + ks * 32;
                float4 f0 = *(const float4*)rp;
                float4 f1 = *(const float4*)(rp + 4);
                float f[8] = {f0.x, f0.y, f0.z, f0.w, f1.x, f1.y, f1.z, f1.w};
                bf16x8 H, L;
#pragma unroll
                for (int j = 0; j < 8; ++j) {
                    unsigned hb = bf16u(f[j]);
                    H[j] = (short)hb;
                    L[j] = (short)bf16u(f[j] - bf16back(hb));
                }
                aH[mt] = H;
                aL[mt] = L;
            }
#pragma unroll
            for (int nt = 0; nt < 8; ++nt) {
                int wb = ((ksg * 8 + nt) * 64 + lane) * 8;
                bf16x8 bH = *(const bf16x8*)&wf_hi[wb];
                bf16x8 bL = *(const bf16x8*)&wf_lo[wb];
#pragma unroll
                for (int mt = 0; mt < 2; ++mt) {
                    acc[mt][nt] = __builtin_amdgcn_mfma_f32_16x16x32_bf16(aH[mt], bH, acc[mt][nt], 0, 0, 0);
                    acc[mt][nt] = __builtin_amdgcn_mfma_f32_16x16x32_bf16(aL[mt], bH, acc[mt][nt], 0, 0, 0);
                    acc[mt][nt] = __builtin_amdgcn_mfma_f32_16x16x32_bf16(aH[mt], bL, acc[mt][nt], 0, 0, 0);
                }
            }
        }
    }

    // ---- epilogue: bias+BN folded, C/D layout scatter ----
#pragma unroll
    for (int nt = 0; nt < 8; ++nt) {
        int c = nt * 16 + l15;
        float As = bn_g[c] * rsqrtf(bn_v[c] + EPS_BN);
        float Cs = (bias[c] - bn_m[c]) * As + bn_b[c];
#pragma unroll
        for (int mt = 0; mt < 2; ++mt) {
#pragma unroll
            for (int r = 0; r < 4; ++r) {
                int gn = node0 + wv * 32 + mt * 16 + quad * 4 + r;
                if (gn < n) {
                    float v = acc[mt][nt][r] * As + Cs;
                    if (RELU) v = fmaxf(v, 0.0f);
                    out[(size_t)gn * 128 + c] = v;
                }
            }
        }
    }
}

// ===========================================================================
// L2-normalize + logits (one wave per node)
// ===========================================================================
__global__ void k_norm_logits(float* __restrict__ emb, float* __restrict__ logits,
                              const float* __restrict__ Wc, const float* __restrict__ bc,
                              int n) {
    int gtid = blockIdx.x * blockDim.x + threadIdx.x;
    int node = gtid >> 6;
    int lane = threadIdx.x & 63;
    if (node >= n) return;

    float* row = emb + (size_t)node * 128;
    float a = row[lane];
    float b = row[lane + 64];

    float ss = a * a + b * b;
#pragma unroll
    for (int off = 32; off; off >>= 1) ss += __shfl_down(ss, off, 64);
    ss = __shfl(ss, 0, 64);

    float inv = 1.0f / fmaxf(sqrtf(ss), EPS_NORM);
    a *= inv;
    b *= inv;
    row[lane] = a;
    row[lane + 64] = b;

    float l0 = a * Wc[lane * 2 + 0] + b * Wc[(lane + 64) * 2 + 0];
    float l1 = a * Wc[lane * 2 + 1] + b * Wc[(lane + 64) * 2 + 1];
#pragma unroll
    for (int off = 32; off; off >>= 1) {
        l0 += __shfl_down(l0, off, 64);
        l1 += __shfl_down(l1, off, 64);
    }
    if (lane == 0) {
        logits[(size_t)node * 2 + 0] = l0 + bc[0];
        logits[(size_t)node * 2 + 1] = l1 + bc[1];
    }
}

// ===========================================================================
extern "C" void kernel_launch(void* const* d_in, const int* in_sizes, int n_in,
                              void* d_out, int out_size, void* d_ws, size_t ws_size,
                              hipStream_t stream) {
    const float* x    = (const float*)d_in[0];
    const int*   ei   = (const int*)d_in[1];
    const int*   src  = ei;
    const int*   dstp = ei + N_EDGES;

    const float* W1l = (const float*)d_in[2];
    const float* W1r = (const float*)d_in[3];
    const float* b1  = (const float*)d_in[4];
    const float* g1  = (const float*)d_in[5];
    const float* bb1 = (const float*)d_in[6];
    const float* m1  = (const float*)d_in[7];
    const float* v1  = (const float*)d_in[8];

    const float* W2l = (const float*)d_in[9];
    const float* W2r = (const float*)d_in[10];
    const float* b2  = (const float*)d_in[11];
    const float* g2  = (const float*)d_in[12];
    const float* bb2 = (const float*)d_in[13];
    const float* m2  = (const float*)d_in[14];
    const float* v2  = (const float*)d_in[15];

    const float* W3l = (const float*)d_in[16];
    const float* W3r = (const float*)d_in[17];
    const float* b3  = (const float*)d_in[18];
    const float* g3  = (const float*)d_in[19];
    const float* bb3 = (const float*)d_in[20];
    const float* m3  = (const float*)d_in[21];
    const float* v3  = (const float*)d_in[22];

    const float* Wc = (const float*)d_in[23];
    const float* bc = (const float*)d_in[24];

    // workspace layout (4-byte base units; wf arrays are ushort)
    float* inv   = (float*)d_ws;                        // N
    int*   deg   = (int*)(inv + N_NODES);               // N
    int*   offs  = deg + N_NODES;                       // N+1
    int*   cursor= offs + N_NODES + 1;                  // N
    int*   adj   = cursor + N_NODES;                    // E
    int*   bsum  = adj + N_EDGES;                       // 512
    unsigned short* wf2h = (unsigned short*)(bsum + 512);  // 16384
    unsigned short* wf2l = wf2h + 16384;                   // 16384
    unsigned short* wf3h = wf2l + 16384;                   // 32768
    unsigned short* wf3l = wf3h + 32768;                   // 32768
    float* agg   = (float*)(wf3l + 32768);              // N*128 (mean buffer)
    float* h1    = agg + (size_t)N_NODES * 128;         // N*64
    float* h2    = h1 + (size_t)N_NODES * 64;           // N*128

    float* emb    = (float*)d_out;
    float* logits = emb + (size_t)N_NODES * 128;

    const int B = 256;
    const int nb = (N_NODES + 255) / 256;               // 391 <= 512
    const int nMfBlocks = (N_NODES + 127) / 128;        // 782
    const int nWaveBlocks = ((size_t)N_NODES * 64 + B - 1) / B;

    // ---- CSR build + weight pre-swizzle (independent of layer outputs) ----
    hipMemsetAsync(deg, 0, N_NODES * sizeof(int), stream);
    k_deg<<<(N_EDGES + B - 1) / B, B, 0, stream>>>(dstp, deg, N_EDGES);
    k_scan1<<<nb, 256, 0, stream>>>(deg, offs, bsum, N_NODES);
    k_scan2<<<1, 512, 0, stream>>>(bsum, nb);
    k_prep<<<nb, 256, 0, stream>>>(offs, bsum, deg, cursor, inv, N_NODES, N_EDGES);
    k_fill<<<(N_EDGES + B - 1) / B, B, 0, stream>>>(src, dstp, cursor, adj, N_EDGES);
    k_wprep<64><<<(128 * 128) / 256, 256, 0, stream>>>(W2l, W2r, wf2h, wf2l);
    k_wprep<128><<<(256 * 128) / 256, 256, 0, stream>>>(W3l, W3r, wf3h, wf3l);

    // ---- layer 1: 10 -> 64, ReLU ----
    k_gather10<<<nWaveBlocks, B, 0, stream>>>(x, adj, offs, inv, agg, N_NODES);
    k_linear<10, 64, true><<<((size_t)N_NODES * 64 + B - 1) / B, B, 0, stream>>>(
        x, agg, W1l, W1r, b1, g1, bb1, m1, v1, h1, N_NODES);

    // ---- layer 2: 64 -> 128, ReLU ----
    k_gather64<<<nWaveBlocks, B, 0, stream>>>(h1, adj, offs, inv, agg, N_NODES);
    k_linear_mfma<64, true><<<nMfBlocks, 256, 0, stream>>>(
        h1, agg, wf2h, wf2l, b2, g2, bb2, m2, v2, h2, N_NODES);

    // ---- layer 3: 128 -> 128, no ReLU, into d_out emb region ----
    k_gather128<<<nWaveBlocks, B, 0, stream>>>(h2, adj, offs, inv, agg, N_NODES);
    k_linear_mfma<128, false><<<nMfBlocks, 256, 0, stream>>>(
        h2, agg, wf3h, wf3l, b3, g3, bb3, m3, v3, emb, N_NODES);

    // ---- normalize + logits ----
    k_norm_logits<<<nWaveBlocks, B, 0, stream>>>(emb, logits, Wc, bc, N_NODES);
}

// Round 3
// 437.942 us; speedup vs baseline: 1.1932x; 1.1339x over previous
//
#include <hip/hip_runtime.h>

#define N_NODES 100000
#define N_EDGES 600000
#define EPS_BN 1e-5f
#define EPS_NORM 1e-12f

typedef __attribute__((ext_vector_type(8))) short bf16x8;
typedef __attribute__((ext_vector_type(4))) float f32x4;

__device__ inline unsigned bf16u(float x) {
    unsigned b = __float_as_uint(x);
    return (b + 0x7FFF + ((b >> 16) & 1)) >> 16;
}
__device__ inline float bf16back(unsigned hb) { return __uint_as_float(hb << 16); }

// ===========================================================================
// CSR build: degree histogram -> exclusive scan -> cursor fill
// ===========================================================================
__global__ void k_deg(const int* __restrict__ dst, int* __restrict__ deg, int E) {
    int e = blockIdx.x * blockDim.x + threadIdx.x;
    if (e < E) atomicAdd(&deg[dst[e]], 1);
}

__global__ void k_scan1(const int* __restrict__ in, int* __restrict__ out,
                        int* __restrict__ bsum, int n) {
    __shared__ int s[256];
    int i = blockIdx.x * 256 + threadIdx.x;
    int v = (i < n) ? in[i] : 0;
    s[threadIdx.x] = v;
    __syncthreads();
#pragma unroll
    for (int off = 1; off < 256; off <<= 1) {
        int t = (threadIdx.x >= off) ? s[threadIdx.x - off] : 0;
        __syncthreads();
        s[threadIdx.x] += t;
        __syncthreads();
    }
    if (i < n) out[i] = s[threadIdx.x] - v;
    if (threadIdx.x == 255) bsum[blockIdx.x] = s[255];
}

__global__ void k_scan2(int* __restrict__ bsum, int nb) {
    __shared__ int s[512];
    int v = (threadIdx.x < nb) ? bsum[threadIdx.x] : 0;
    s[threadIdx.x] = v;
    __syncthreads();
#pragma unroll
    for (int off = 1; off < 512; off <<= 1) {
        int t = (threadIdx.x >= off) ? s[threadIdx.x - off] : 0;
        __syncthreads();
        s[threadIdx.x] += t;
        __syncthreads();
    }
    if (threadIdx.x < nb) bsum[threadIdx.x] = s[threadIdx.x] - v;
}

__global__ void k_prep(int* __restrict__ offs, const int* __restrict__ bsum,
                       const int* __restrict__ deg, int* __restrict__ cursor,
                       float* __restrict__ inv, int n, int E) {
    int i = blockIdx.x * 256 + threadIdx.x;
    if (i >= n) return;
    int o = offs[i] + bsum[i >> 8];
    offs[i] = o;
    cursor[i] = o;
    inv[i] = 1.0f / fmaxf((float)deg[i], 1.0f);
    if (i == 0) offs[n] = E;
}

__global__ void k_fill(const int* __restrict__ src, const int* __restrict__ dst,
                       int* __restrict__ cursor, int* __restrict__ adj, int E) {
    int e = blockIdx.x * blockDim.x + threadIdx.x;
    if (e < E) {
        int pos = atomicAdd(&cursor[dst[e]], 1);
        adj[pos] = src[e];
    }
}

// ===========================================================================
// Gather-aggregate (mean), DIN=10: one wave per node, 4 lane-groups of 16
// each handling one neighbor per iteration (serial chain depth deg/4 instead
// of deg). Cross-group combine via 2x shfl_xor.
// ===========================================================================
__global__ void k_gather10(const float* __restrict__ h, const int* __restrict__ adj,
                           const int* __restrict__ offs, const float* __restrict__ inv,
                           float* __restrict__ mean, int n) {
    int node = (blockIdx.x * blockDim.x + threadIdx.x) >> 6;
    int lane = threadIdx.x & 63;
    if (node >= n) return;
    int beg = offs[node], end = offs[node + 1];
    float iv = inv[node];
    int grp = lane >> 4;       // 0..3: neighbor sub-slot
    int gl = lane & 15;        // dim within group (10 active)
    bool act = gl < 10;
    float acc = 0.0f;
    for (int p0 = beg; p0 < end; p0 += 4) {
        int p = p0 + grp;
        if (p < end && act) {
            int s = adj[p];
            acc += h[(size_t)s * 10 + gl];
        }
    }
    acc += __shfl_xor(acc, 16, 64);
    acc += __shfl_xor(acc, 32, 64);
    if (lane < 10) mean[(size_t)node * 10 + lane] = acc * iv;
}

__global__ void k_gather64(const float* __restrict__ h, const int* __restrict__ adj,
                           const int* __restrict__ offs, const float* __restrict__ inv,
                           float* __restrict__ mean, int n) {
    int node = (blockIdx.x * blockDim.x + threadIdx.x) >> 6;
    int lane = threadIdx.x & 63;
    if (node >= n) return;
    int beg = offs[node], end = offs[node + 1];
    float iv = inv[node];
    float a0 = 0.0f, a1 = 0.0f, a2 = 0.0f, a3 = 0.0f;
    int p = beg;
    for (; p + 4 <= end; p += 4) {
        int s0 = adj[p], s1 = adj[p + 1], s2 = adj[p + 2], s3 = adj[p + 3];
        a0 += h[(size_t)s0 * 64 + lane];
        a1 += h[(size_t)s1 * 64 + lane];
        a2 += h[(size_t)s2 * 64 + lane];
        a3 += h[(size_t)s3 * 64 + lane];
    }
    for (; p < end; ++p) a0 += h[(size_t)adj[p] * 64 + lane];
    mean[(size_t)node * 64 + lane] = ((a0 + a1) + (a2 + a3)) * iv;
}

__global__ void k_gather128(const float* __restrict__ h, const int* __restrict__ adj,
                            const int* __restrict__ offs, const float* __restrict__ inv,
                            float* __restrict__ mean, int n) {
    int node = (blockIdx.x * blockDim.x + threadIdx.x) >> 6;
    int lane = threadIdx.x & 63;
    if (node >= n) return;
    int beg = offs[node], end = offs[node + 1];
    float iv = inv[node];
    float2 a0 = {0, 0}, a1 = {0, 0}, a2 = {0, 0}, a3 = {0, 0};
    int p = beg;
    for (; p + 4 <= end; p += 4) {
        int s0 = adj[p], s1 = adj[p + 1], s2 = adj[p + 2], s3 = adj[p + 3];
        float2 v0 = *(const float2*)&h[(size_t)s0 * 128 + lane * 2];
        float2 v1 = *(const float2*)&h[(size_t)s1 * 128 + lane * 2];
        float2 v2 = *(const float2*)&h[(size_t)s2 * 128 + lane * 2];
        float2 v3 = *(const float2*)&h[(size_t)s3 * 128 + lane * 2];
        a0.x += v0.x; a0.y += v0.y;
        a1.x += v1.x; a1.y += v1.y;
        a2.x += v2.x; a2.y += v2.y;
        a3.x += v3.x; a3.y += v3.y;
    }
    for (; p < end; ++p) {
        float2 v0 = *(const float2*)&h[(size_t)adj[p] * 128 + lane * 2];
        a0.x += v0.x; a0.y += v0.y;
    }
    float2 o = {((a0.x + a1.x) + (a2.x + a3.x)) * iv,
                ((a0.y + a1.y) + (a2.y + a3.y)) * iv};
    *(float2*)&mean[(size_t)node * 128 + lane * 2] = o;
}

// ===========================================================================
// Simple linear (layer 1: DIN=10, DOUT=64). mean already divided.
// ===========================================================================
template <int DIN, int DOUT, bool RELU>
__global__ void k_linear(const float* __restrict__ h, const float* __restrict__ mean,
                         const float* __restrict__ Wl, const float* __restrict__ Wr,
                         const float* __restrict__ bias,
                         const float* __restrict__ bn_g, const float* __restrict__ bn_b,
                         const float* __restrict__ bn_m, const float* __restrict__ bn_v,
                         float* __restrict__ out, int n) {
    int tid = blockIdx.x * blockDim.x + threadIdx.x;
    int node = tid / DOUT;
    int c = tid - node * DOUT;
    if (node >= n) return;

    const float* hr = h + (size_t)node * DIN;
    const float* mr = mean + (size_t)node * DIN;

    float acc = bias[c];
#pragma unroll
    for (int k = 0; k < DIN; ++k) {
        acc += mr[k] * Wl[k * DOUT + c] + hr[k] * Wr[k * DOUT + c];
    }
    float o = (acc - bn_m[c]) * rsqrtf(bn_v[c] + EPS_BN) * bn_g[c] + bn_b[c];
    if (RELU) o = fmaxf(o, 0.0f);
    out[(size_t)node * DOUT + c] = o;
}

// ===========================================================================
// Weight pre-swizzle into MFMA B-fragment order (hi/lo bf16 split).
// W = [Wl; Wr] stacked (K=2*DIN rows, 128 cols). B-frag layout for
// mfma_f32_16x16x32_bf16: lane holds n=lane&15, k=quad*8+j (j contiguous).
// wf[((ks*8+nt)*64+lane)*8+j] so the kernel loads 16 B/lane coalesced.
// ===========================================================================
template <int DIN>
__global__ void k_wprep(const float* __restrict__ Wl, const float* __restrict__ Wr,
                        unsigned short* __restrict__ wf_hi,
                        unsigned short* __restrict__ wf_lo) {
    constexpr int K = 2 * DIN;
    int t = blockIdx.x * 256 + threadIdx.x;
    if (t >= K * 128) return;
    int j = t & 7;
    int lane = (t >> 3) & 63;
    int nt = (t >> 9) & 7;
    int ks = t >> 12;
    int k = ks * 32 + (lane >> 4) * 8 + j;
    int nn = nt * 16 + (lane & 15);
    float v = (k < DIN) ? Wl[k * 128 + nn] : Wr[(k - DIN) * 128 + nn];
    unsigned hb = bf16u(v);
    float r = v - bf16back(hb);
    wf_hi[t] = (unsigned short)hb;
    wf_lo[t] = (unsigned short)bf16u(r);
}

// ===========================================================================
// MFMA linear+BN(+ReLU)(+L2norm+logits), DOUT=128, K=2*DIN ([mean,h]).
// bf16 hi/lo split: acc += Ahi*Bhi + Alo*Bhi + Ahi*Blo. No LDS, no
// barriers: A-frags (m=lane&15, k=quad*8+j) read directly from row-major
// fp32 source as 2x float4/lane, converted in registers. B-frags from
// pre-swizzled global (L2-hot).
// NORM path (layer 3): in C/D layout the 16 lanes of one quad all hold the
// SAME output row gn (channels c=nt*16+l15), so the row L2-norm and the
// 128x2 logits matvec reduce with 4x shfl_xor(1,2,4,8) each -- saves the
// separate 51 MB read+write k_norm_logits pass entirely.
// ===========================================================================
template <int DIN, bool RELU, bool NORM>
__global__ __launch_bounds__(256) void k_linear_mfma(
    const float* __restrict__ h, const float* __restrict__ mean,
    const unsigned short* __restrict__ wf_hi, const unsigned short* __restrict__ wf_lo,
    const float* __restrict__ bias,
    const float* __restrict__ bn_g, const float* __restrict__ bn_b,
    const float* __restrict__ bn_m, const float* __restrict__ bn_v,
    float* __restrict__ out, int n,
    const float* __restrict__ Wc, const float* __restrict__ bc,
    float* __restrict__ logits) {
    constexpr int CH = (2 * DIN) / 64;  // 64-k chunks

    const int tid = threadIdx.x;
    const int lane = tid & 63;
    const int wv = tid >> 6;
    const int quad = lane >> 4;
    const int l15 = lane & 15;
    const int node0 = blockIdx.x * 128;

    // clamped row indices for this lane's two m-tiles (A-frag rows)
    int row0 = node0 + wv * 32 + l15;
    int row1 = row0 + 16;
    if (row0 > n - 1) row0 = n - 1;
    if (row1 > n - 1) row1 = n - 1;

    f32x4 acc[2][8];
#pragma unroll
    for (int mt = 0; mt < 2; ++mt)
#pragma unroll
        for (int nt = 0; nt < 8; ++nt) acc[mt][nt] = {0.0f, 0.0f, 0.0f, 0.0f};

    for (int cc = 0; cc < CH; ++cc) {
        const int kbase = cc * 64;
        const float* srcp = (kbase < DIN) ? mean : h;
        const int coloff = ((kbase < DIN) ? kbase : kbase - DIN) + quad * 8;

        const float* rp0 = srcp + (size_t)row0 * DIN + coloff;
        const float* rp1 = srcp + (size_t)row1 * DIN + coloff;

#pragma unroll
        for (int ks = 0; ks < 2; ++ks) {
            const int ksg = cc * 2 + ks;
            // ---- direct A-fragment loads + fp32 -> bf16 hi/lo in registers
            bf16x8 aH[2], aL[2];
#pragma unroll
            for (int mt = 0; mt < 2; ++mt) {
                const float* rp = (mt == 0 ? rp0 : rp1) + ks * 32;
                float4 f0 = *(const float4*)rp;
                float4 f1 = *(const float4*)(rp + 4);
                float f[8] = {f0.x, f0.y, f0.z, f0.w, f1.x, f1.y, f1.z, f1.w};
                bf16x8 H, L;
#pragma unroll
                for (int j = 0; j < 8; ++j) {
                    unsigned hb = bf16u(f[j]);
                    H[j] = (short)hb;
                    L[j] = (short)bf16u(f[j] - bf16back(hb));
                }
                aH[mt] = H;
                aL[mt] = L;
            }
#pragma unroll
            for (int nt = 0; nt < 8; ++nt) {
                int wb = ((ksg * 8 + nt) * 64 + lane) * 8;
                bf16x8 bH = *(const bf16x8*)&wf_hi[wb];
                bf16x8 bL = *(const bf16x8*)&wf_lo[wb];
#pragma unroll
                for (int mt = 0; mt < 2; ++mt) {
                    acc[mt][nt] = __builtin_amdgcn_mfma_f32_16x16x32_bf16(aH[mt], bH, acc[mt][nt], 0, 0, 0);
                    acc[mt][nt] = __builtin_amdgcn_mfma_f32_16x16x32_bf16(aL[mt], bH, acc[mt][nt], 0, 0, 0);
                    acc[mt][nt] = __builtin_amdgcn_mfma_f32_16x16x32_bf16(aH[mt], bL, acc[mt][nt], 0, 0, 0);
                }
            }
        }
    }

    // ---- epilogue: bias+BN folded ----
    float As[8], Cs[8];
#pragma unroll
    for (int nt = 0; nt < 8; ++nt) {
        int c = nt * 16 + l15;
        As[nt] = bn_g[c] * rsqrtf(bn_v[c] + EPS_BN);
        Cs[nt] = (bias[c] - bn_m[c]) * As[nt] + bn_b[c];
    }

    if (!NORM) {
#pragma unroll
        for (int nt = 0; nt < 8; ++nt) {
            int c = nt * 16 + l15;
#pragma unroll
            for (int mt = 0; mt < 2; ++mt) {
#pragma unroll
                for (int r = 0; r < 4; ++r) {
                    int gn = node0 + wv * 32 + mt * 16 + quad * 4 + r;
                    if (gn < n) {
                        float v = acc[mt][nt][r] * As[nt] + Cs[nt];
                        if (RELU) v = fmaxf(v, 0.0f);
                        out[(size_t)gn * 128 + c] = v;
                    }
                }
            }
        }
    } else {
        float wc0[8], wc1[8];
#pragma unroll
        for (int nt = 0; nt < 8; ++nt) {
            int c = nt * 16 + l15;
            wc0[nt] = Wc[c * 2 + 0];
            wc1[nt] = Wc[c * 2 + 1];
        }
        float bc0 = bc[0], bc1 = bc[1];
#pragma unroll
        for (int mt = 0; mt < 2; ++mt) {
#pragma unroll
            for (int r = 0; r < 4; ++r) {
                int gn = node0 + wv * 32 + mt * 16 + quad * 4 + r;
                float v[8];
                float ss = 0.0f;
#pragma unroll
                for (int nt = 0; nt < 8; ++nt) {
                    v[nt] = acc[mt][nt][r] * As[nt] + Cs[nt];
                    ss += v[nt] * v[nt];
                }
                ss += __shfl_xor(ss, 1, 64);
                ss += __shfl_xor(ss, 2, 64);
                ss += __shfl_xor(ss, 4, 64);
                ss += __shfl_xor(ss, 8, 64);
                float is = 1.0f / fmaxf(sqrtf(ss), EPS_NORM);
                float l0 = 0.0f, l1 = 0.0f;
#pragma unroll
                for (int nt = 0; nt < 8; ++nt) {
                    float e = v[nt] * is;
                    if (gn < n) out[(size_t)gn * 128 + nt * 16 + l15] = e;
                    l0 += e * wc0[nt];
                    l1 += e * wc1[nt];
                }
                l0 += __shfl_xor(l0, 1, 64);
                l0 += __shfl_xor(l0, 2, 64);
                l0 += __shfl_xor(l0, 4, 64);
                l0 += __shfl_xor(l0, 8, 64);
                l1 += __shfl_xor(l1, 1, 64);
                l1 += __shfl_xor(l1, 2, 64);
                l1 += __shfl_xor(l1, 4, 64);
                l1 += __shfl_xor(l1, 8, 64);
                if (gn < n && l15 == 0) {
                    logits[(size_t)gn * 2 + 0] = l0 + bc0;
                    logits[(size_t)gn * 2 + 1] = l1 + bc1;
                }
            }
        }
    }
}

// ===========================================================================
extern "C" void kernel_launch(void* const* d_in, const int* in_sizes, int n_in,
                              void* d_out, int out_size, void* d_ws, size_t ws_size,
                              hipStream_t stream) {
    const float* x    = (const float*)d_in[0];
    const int*   ei   = (const int*)d_in[1];
    const int*   src  = ei;
    const int*   dstp = ei + N_EDGES;

    const float* W1l = (const float*)d_in[2];
    const float* W1r = (const float*)d_in[3];
    const float* b1  = (const float*)d_in[4];
    const float* g1  = (const float*)d_in[5];
    const float* bb1 = (const float*)d_in[6];
    const float* m1  = (const float*)d_in[7];
    const float* v1  = (const float*)d_in[8];

    const float* W2l = (const float*)d_in[9];
    const float* W2r = (const float*)d_in[10];
    const float* b2  = (const float*)d_in[11];
    const float* g2  = (const float*)d_in[12];
    const float* bb2 = (const float*)d_in[13];
    const float* m2  = (const float*)d_in[14];
    const float* v2  = (const float*)d_in[15];

    const float* W3l = (const float*)d_in[16];
    const float* W3r = (const float*)d_in[17];
    const float* b3  = (const float*)d_in[18];
    const float* g3  = (const float*)d_in[19];
    const float* bb3 = (const float*)d_in[20];
    const float* m3  = (const float*)d_in[21];
    const float* v3  = (const float*)d_in[22];

    const float* Wc = (const float*)d_in[23];
    const float* bc = (const float*)d_in[24];

    // workspace layout (4-byte base units; wf arrays are ushort)
    float* inv   = (float*)d_ws;                        // N
    int*   deg   = (int*)(inv + N_NODES);               // N
    int*   offs  = deg + N_NODES;                       // N+1
    int*   cursor= offs + N_NODES + 1;                  // N
    int*   adj   = cursor + N_NODES;                    // E
    int*   bsum  = adj + N_EDGES;                       // 512
    unsigned short* wf2h = (unsigned short*)(bsum + 512);  // 16384
    unsigned short* wf2l = wf2h + 16384;                   // 16384
    unsigned short* wf3h = wf2l + 16384;                   // 32768
    unsigned short* wf3l = wf3h + 32768;                   // 32768
    float* agg   = (float*)(wf3l + 32768);              // N*128 (mean buffer)
    float* h1    = agg + (size_t)N_NODES * 128;         // N*64
    float* h2    = h1 + (size_t)N_NODES * 64;           // N*128

    float* emb    = (float*)d_out;
    float* logits = emb + (size_t)N_NODES * 128;

    const int B = 256;
    const int nb = (N_NODES + 255) / 256;               // 391 <= 512
    const int nMfBlocks = (N_NODES + 127) / 128;        // 782
    const int nWaveBlocks = ((size_t)N_NODES * 64 + B - 1) / B;

    // ---- CSR build + weight pre-swizzle (independent of layer outputs) ----
    hipMemsetAsync(deg, 0, N_NODES * sizeof(int), stream);
    k_deg<<<(N_EDGES + B - 1) / B, B, 0, stream>>>(dstp, deg, N_EDGES);
    k_scan1<<<nb, 256, 0, stream>>>(deg, offs, bsum, N_NODES);
    k_scan2<<<1, 512, 0, stream>>>(bsum, nb);
    k_prep<<<nb, 256, 0, stream>>>(offs, bsum, deg, cursor, inv, N_NODES, N_EDGES);
    k_fill<<<(N_EDGES + B - 1) / B, B, 0, stream>>>(src, dstp, cursor, adj, N_EDGES);
    k_wprep<64><<<(128 * 128) / 256, 256, 0, stream>>>(W2l, W2r, wf2h, wf2l);
    k_wprep<128><<<(256 * 128) / 256, 256, 0, stream>>>(W3l, W3r, wf3h, wf3l);

    // ---- layer 1: 10 -> 64, ReLU ----
    k_gather10<<<nWaveBlocks, B, 0, stream>>>(x, adj, offs, inv, agg, N_NODES);
    k_linear<10, 64, true><<<((size_t)N_NODES * 64 + B - 1) / B, B, 0, stream>>>(
        x, agg, W1l, W1r, b1, g1, bb1, m1, v1, h1, N_NODES);

    // ---- layer 2: 64 -> 128, ReLU ----
    k_gather64<<<nWaveBlocks, B, 0, stream>>>(h1, adj, offs, inv, agg, N_NODES);
    k_linear_mfma<64, true, false><<<nMfBlocks, 256, 0, stream>>>(
        h1, agg, wf2h, wf2l, b2, g2, bb2, m2, v2, h2, N_NODES,
        nullptr, nullptr, nullptr);

    // ---- layer 3: 128 -> 128, no ReLU, fused L2-norm + logits, into d_out
    k_gather128<<<nWaveBlocks, B, 0, stream>>>(h2, adj, offs, inv, agg, N_NODES);
    k_linear_mfma<128, false, true><<<nMfBlocks, 256, 0, stream>>>(
        h2, agg, wf3h, wf3l, b3, g3, bb3, m3, v3, emb, N_NODES,
        Wc, bc, logits);
}